// Round 1
// baseline (5905.426 us; speedup 1.0000x reference)
//
#include <hip/hip_runtime.h>
#include <hip/hip_bf16.h>

#define N_NODES 50000
#define VOCAB   2048
#define HID     256
#define N_EDGES 1600000

typedef __attribute__((ext_vector_type(8))) __bf16 bf16x8;
typedef __attribute__((ext_vector_type(4))) __bf16 bf16x4;
typedef __attribute__((ext_vector_type(4))) float  f32x4;

// ---------------------------------------------------------------------------
// GEMM with B^T input: C[M][N] = A[M][K] * B[N][K]^T  (+ bias, + relu on A)
// bf16 MFMA 16x16x32, 128x128 tile, BK=32, 4 waves (2x2), fp32 in/out.
// ---------------------------------------------------------------------------
template<bool RELU_A, bool BIAS>
__global__ __launch_bounds__(256) void gemm_bt(
    const float* __restrict__ A,     // [M][K]
    const float* __restrict__ B,     // [N][K]
    const float* __restrict__ bias,  // [N] or nullptr
    float* __restrict__ C,           // [M][N]
    int M, int N, int K)
{
    constexpr int BM = 128, BN = 128, BK = 32;
    constexpr int LDS = 40;  // 32 + 8 pad -> 80B row stride, 2-way bank alias (free)
    __shared__ __bf16 sA[BM * LDS];
    __shared__ __bf16 sB[BN * LDS];

    const int tid  = threadIdx.x;
    const int lane = tid & 63;
    const int wid  = tid >> 6;
    const int wm   = wid >> 1;       // wave row 0..1
    const int wn   = wid & 1;        // wave col 0..1
    const int half = lane >> 4;      // k-group 0..3
    const int r16  = lane & 15;

    const int m0 = blockIdx.x * BM;
    const int n0 = blockIdx.y * BN;

    f32x4 acc[4][4] = {};

    const int nk = K / BK;           // K is always a multiple of 32 here
    for (int kt = 0; kt < nk; ++kt) {
        const int k0 = kt * BK;
        // --- stage A,B tiles: 128x32 fp32 each = 1024 float4 slots each ---
        #pragma unroll
        for (int i = 0; i < 4; ++i) {
            const int s  = tid + i * 256;   // 0..1023
            const int r  = s >> 3;          // tile row
            const int cg = s & 7;           // float4 group within row
            // A (guard M edge, optional relu)
            float4 va = make_float4(0.f, 0.f, 0.f, 0.f);
            const int gr = m0 + r;
            if (gr < M)
                va = *(const float4*)&A[(size_t)gr * K + k0 + cg * 4];
            if (RELU_A) {
                va.x = fmaxf(va.x, 0.f); va.y = fmaxf(va.y, 0.f);
                va.z = fmaxf(va.z, 0.f); va.w = fmaxf(va.w, 0.f);
            }
            bf16x4 pa = { (__bf16)va.x, (__bf16)va.y, (__bf16)va.z, (__bf16)va.w };
            *(bf16x4*)&sA[r * LDS + cg * 4] = pa;
            // B (N is a multiple of 128 for both GEMMs -> no guard)
            const float4 vb = *(const float4*)&B[(size_t)(n0 + r) * K + k0 + cg * 4];
            bf16x4 pb = { (__bf16)vb.x, (__bf16)vb.y, (__bf16)vb.z, (__bf16)vb.w };
            *(bf16x4*)&sB[r * LDS + cg * 4] = pb;
        }
        __syncthreads();

        // --- MFMA: each wave computes 64x64 = 4x4 fragments of 16x16 ---
        bf16x8 af[4], bf[4];
        #pragma unroll
        for (int m = 0; m < 4; ++m)
            af[m] = *(const bf16x8*)&sA[(wm * 64 + m * 16 + r16) * LDS + half * 8];
        #pragma unroll
        for (int n = 0; n < 4; ++n)
            bf[n] = *(const bf16x8*)&sB[(wn * 64 + n * 16 + r16) * LDS + half * 8];
        #pragma unroll
        for (int m = 0; m < 4; ++m)
            #pragma unroll
            for (int n = 0; n < 4; ++n)
                acc[m][n] = __builtin_amdgcn_mfma_f32_16x16x32_bf16(
                                af[m], bf[n], acc[m][n], 0, 0, 0);
        __syncthreads();
    }

    // --- epilogue: C/D layout col=lane&15, row=(lane>>4)*4+j (m89-verified) ---
    #pragma unroll
    for (int m = 0; m < 4; ++m) {
        const int rbase = m0 + wm * 64 + m * 16 + half * 4;
        #pragma unroll
        for (int j = 0; j < 4; ++j) {
            const int gr = rbase + j;
            if (gr >= M) continue;
            #pragma unroll
            for (int n = 0; n < 4; ++n) {
                const int gc = n0 + wn * 64 + n * 16 + r16;
                float o = acc[m][n][j];
                if (BIAS) o += bias[gc];
                C[(size_t)gr * N + gc] = o;
            }
        }
    }
}

// ---------------------------------------------------------------------------
// SpMM (COO scatter): agg[row] += val * support[col]; one wave per edge,
// lane covers 4 of the 256 hidden dims. Native fp32 atomics.
// ---------------------------------------------------------------------------
__global__ __launch_bounds__(256) void spmm_atomic(
    const int*   __restrict__ arow,
    const int*   __restrict__ acol,
    const float* __restrict__ aval,
    const float* __restrict__ support,
    float*       __restrict__ agg,
    int E)
{
    const int lane = threadIdx.x & 63;
    const int w    = blockIdx.x * (blockDim.x >> 6) + (threadIdx.x >> 6);
    const int nw   = gridDim.x * (blockDim.x >> 6);
    for (int e = w; e < E; e += nw) {
        const int   r = arow[e];
        const int   c = acol[e];
        const float v = aval[e];
        const float4 s = *(const float4*)&support[(size_t)c * HID + lane * 4];
        float* dst = &agg[(size_t)r * HID + lane * 4];
        unsafeAtomicAdd(dst + 0, s.x * v);
        unsafeAtomicAdd(dst + 1, s.y * v);
        unsafeAtomicAdd(dst + 2, s.z * v);
        unsafeAtomicAdd(dst + 3, s.w * v);
    }
}

extern "C" void kernel_launch(void* const* d_in, const int* in_sizes, int n_in,
                              void* d_out, int out_size, void* d_ws, size_t ws_size,
                              hipStream_t stream) {
    const float* context  = (const float*)d_in[0];   // [N_NODES][VOCAB]
    const int*   adj_row  = (const int*)  d_in[1];   // [E]
    const int*   adj_col  = (const int*)  d_in[2];   // [E]
    const float* adj_val  = (const float*)d_in[3];   // [E]
    const float* ctx_w    = (const float*)d_in[4];   // [HID][VOCAB]
    const float* out_w    = (const float*)d_in[5];   // [VOCAB][HID]
    const float* out_b    = (const float*)d_in[6];   // [VOCAB]
    float*       out      = (float*)d_out;           // [N_NODES][VOCAB]

    float* support = (float*)d_ws;                       // [N_NODES][HID]
    float* agg     = support + (size_t)N_NODES * HID;    // [N_NODES][HID]

    // zero the scatter accumulator (graph-capture legal)
    hipMemsetAsync(agg, 0, (size_t)N_NODES * HID * sizeof(float), stream);

    const dim3 blk(256);

    // GEMM1: support = context @ ctx_w^T   (M=50000, N=256, K=2048)
    dim3 g1((N_NODES + 127) / 128, HID / 128);
    gemm_bt<false, false><<<g1, blk, 0, stream>>>(
        context, ctx_w, nullptr, support, N_NODES, HID, VOCAB);

    // SpMM: agg[r] += val * support[c]
    spmm_atomic<<<4096, blk, 0, stream>>>(
        adj_row, adj_col, adj_val, support, agg, N_EDGES);

    // GEMM2: out = relu(agg) @ out_w^T + out_b  (M=50000, N=2048, K=256)
    dim3 g2((N_NODES + 127) / 128, VOCAB / 128);
    gemm_bt<true, true><<<g2, blk, 0, stream>>>(
        agg, out_w, out_b, out, N_NODES, VOCAB, HID);
}

// Round 2
// 1102.021 us; speedup vs baseline: 5.3587x; 5.3587x over previous
//
#include <hip/hip_runtime.h>
#include <hip/hip_bf16.h>

#define N_NODES 50000
#define VOCAB   2048
#define HID     256
#define N_EDGES 1600000

typedef __attribute__((ext_vector_type(8))) __bf16 bf16x8;
typedef __attribute__((ext_vector_type(4))) __bf16 bf16x4;
typedef __attribute__((ext_vector_type(4))) float  f32x4;

// ---------------------------------------------------------------------------
// GEMM with B^T input: C[M][N] = A[M][K] * B[N][K]^T  (+ bias, + relu on A)
// bf16 MFMA 16x16x32, 128x128 tile, BK=32, 4 waves (2x2), fp32 in/out.
// ---------------------------------------------------------------------------
template<bool RELU_A, bool BIAS>
__global__ __launch_bounds__(256) void gemm_bt(
    const float* __restrict__ A,     // [M][K]
    const float* __restrict__ B,     // [N][K]
    const float* __restrict__ bias,  // [N] or nullptr
    float* __restrict__ C,           // [M][N]
    int M, int N, int K)
{
    constexpr int BM = 128, BN = 128, BK = 32;
    constexpr int LDS = 40;  // 32 + 8 pad -> 80B row stride, 2-way bank alias (free)
    __shared__ __bf16 sA[BM * LDS];
    __shared__ __bf16 sB[BN * LDS];

    const int tid  = threadIdx.x;
    const int lane = tid & 63;
    const int wid  = tid >> 6;
    const int wm   = wid >> 1;       // wave row 0..1
    const int wn   = wid & 1;        // wave col 0..1
    const int half = lane >> 4;      // k-group 0..3
    const int r16  = lane & 15;

    const int m0 = blockIdx.x * BM;
    const int n0 = blockIdx.y * BN;

    f32x4 acc[4][4] = {};

    const int nk = K / BK;           // K is always a multiple of 32 here
    for (int kt = 0; kt < nk; ++kt) {
        const int k0 = kt * BK;
        // --- stage A,B tiles: 128x32 fp32 each = 1024 float4 slots each ---
        #pragma unroll
        for (int i = 0; i < 4; ++i) {
            const int s  = tid + i * 256;   // 0..1023
            const int r  = s >> 3;          // tile row
            const int cg = s & 7;           // float4 group within row
            // A (guard M edge, optional relu)
            float4 va = make_float4(0.f, 0.f, 0.f, 0.f);
            const int gr = m0 + r;
            if (gr < M)
                va = *(const float4*)&A[(size_t)gr * K + k0 + cg * 4];
            if (RELU_A) {
                va.x = fmaxf(va.x, 0.f); va.y = fmaxf(va.y, 0.f);
                va.z = fmaxf(va.z, 0.f); va.w = fmaxf(va.w, 0.f);
            }
            bf16x4 pa = { (__bf16)va.x, (__bf16)va.y, (__bf16)va.z, (__bf16)va.w };
            *(bf16x4*)&sA[r * LDS + cg * 4] = pa;
            // B (N is a multiple of 128 for both GEMMs -> no guard)
            const float4 vb = *(const float4*)&B[(size_t)(n0 + r) * K + k0 + cg * 4];
            bf16x4 pb = { (__bf16)vb.x, (__bf16)vb.y, (__bf16)vb.z, (__bf16)vb.w };
            *(bf16x4*)&sB[r * LDS + cg * 4] = pb;
        }
        __syncthreads();

        // --- MFMA: each wave computes 64x64 = 4x4 fragments of 16x16 ---
        bf16x8 af[4], bf[4];
        #pragma unroll
        for (int m = 0; m < 4; ++m)
            af[m] = *(const bf16x8*)&sA[(wm * 64 + m * 16 + r16) * LDS + half * 8];
        #pragma unroll
        for (int n = 0; n < 4; ++n)
            bf[n] = *(const bf16x8*)&sB[(wn * 64 + n * 16 + r16) * LDS + half * 8];
        #pragma unroll
        for (int m = 0; m < 4; ++m)
            #pragma unroll
            for (int n = 0; n < 4; ++n)
                acc[m][n] = __builtin_amdgcn_mfma_f32_16x16x32_bf16(
                                af[m], bf[n], acc[m][n], 0, 0, 0);
        __syncthreads();
    }

    // --- epilogue: C/D layout col=lane&15, row=(lane>>4)*4+j (m89-verified) ---
    #pragma unroll
    for (int m = 0; m < 4; ++m) {
        const int rbase = m0 + wm * 64 + m * 16 + half * 4;
        #pragma unroll
        for (int j = 0; j < 4; ++j) {
            const int gr = rbase + j;
            if (gr >= M) continue;
            #pragma unroll
            for (int n = 0; n < 4; ++n) {
                const int gc = n0 + wn * 64 + n * 16 + r16;
                float o = acc[m][n][j];
                if (BIAS) o += bias[gc];
                C[(size_t)gr * N + gc] = o;
            }
        }
    }
}

// ---------------------------------------------------------------------------
// CSR build: histogram -> exclusive scan -> fill (col,val) sorted by row
// ---------------------------------------------------------------------------
__global__ __launch_bounds__(256) void row_histogram(
    const int* __restrict__ arow, int* __restrict__ cnt, int E)
{
    const int t = blockIdx.x * blockDim.x + threadIdx.x;
    const int n = gridDim.x * blockDim.x;
    for (int e = t; e < E; e += n)
        atomicAdd(&cnt[arow[e]], 1);
}

// single-block exclusive scan over n counters (n <= 1024 * chunk)
__global__ __launch_bounds__(1024) void exscan(
    const int* __restrict__ cnt, int* __restrict__ ptr, int n)
{
    __shared__ int s[1024];
    const int t = threadIdx.x;
    const int chunk = (n + 1023) / 1024;
    const int base  = t * chunk;
    int sum = 0;
    for (int i = 0; i < chunk; ++i) {
        const int idx = base + i;
        if (idx < n) sum += cnt[idx];
    }
    s[t] = sum;
    __syncthreads();
    // Hillis-Steele inclusive scan over 1024 partials
    for (int off = 1; off < 1024; off <<= 1) {
        int v = (t >= off) ? s[t - off] : 0;
        __syncthreads();
        s[t] += v;
        __syncthreads();
    }
    int run = (t == 0) ? 0 : s[t - 1];
    for (int i = 0; i < chunk; ++i) {
        const int idx = base + i;
        if (idx < n) { ptr[idx] = run; run += cnt[idx]; }
    }
    if (t == 1023) ptr[n] = run;   // total = E
}

__global__ __launch_bounds__(256) void csr_fill(
    const int*   __restrict__ arow,
    const int*   __restrict__ acol,
    const float* __restrict__ aval,
    const int*   __restrict__ ptr,
    int*         __restrict__ cursor,   // zeroed
    int*         __restrict__ ccol,
    float*       __restrict__ cval,
    int E)
{
    const int t = blockIdx.x * blockDim.x + threadIdx.x;
    const int n = gridDim.x * blockDim.x;
    for (int e = t; e < E; e += n) {
        const int r   = arow[e];
        const int pos = ptr[r] + atomicAdd(&cursor[r], 1);
        ccol[pos] = acol[e];
        cval[pos] = aval[e];
    }
}

// ---------------------------------------------------------------------------
// SpMM gather: one wave per row; lane holds f32x4 of the 256 hidden dims.
// Reads are L3-resident (support = 51 MB); one plain 1 KB store per row.
// ---------------------------------------------------------------------------
__global__ __launch_bounds__(256) void spmm_gather(
    const int*   __restrict__ ptr,
    const int*   __restrict__ ccol,
    const float* __restrict__ cval,
    const float* __restrict__ support,
    float*       __restrict__ agg,
    int n)
{
    const int lane = threadIdx.x & 63;
    const int row  = blockIdx.x * 4 + (threadIdx.x >> 6);
    if (row >= n) return;
    const int beg = ptr[row];
    const int end = ptr[row + 1];

    f32x4 acc = {0.f, 0.f, 0.f, 0.f};
    int i = beg;
    for (; i + 4 <= end; i += 4) {
        const int   c0 = ccol[i],     c1 = ccol[i + 1];
        const int   c2 = ccol[i + 2], c3 = ccol[i + 3];
        const float v0 = cval[i],     v1 = cval[i + 1];
        const float v2 = cval[i + 2], v3 = cval[i + 3];
        const f32x4 s0 = *(const f32x4*)&support[(size_t)c0 * HID + lane * 4];
        const f32x4 s1 = *(const f32x4*)&support[(size_t)c1 * HID + lane * 4];
        const f32x4 s2 = *(const f32x4*)&support[(size_t)c2 * HID + lane * 4];
        const f32x4 s3 = *(const f32x4*)&support[(size_t)c3 * HID + lane * 4];
        acc += v0 * s0;
        acc += v1 * s1;
        acc += v2 * s2;
        acc += v3 * s3;
    }
    for (; i < end; ++i) {
        const int   c = ccol[i];
        const float v = cval[i];
        const f32x4 s = *(const f32x4*)&support[(size_t)c * HID + lane * 4];
        acc += v * s;
    }
    *(f32x4*)&agg[(size_t)row * HID + lane * 4] = acc;
}

extern "C" void kernel_launch(void* const* d_in, const int* in_sizes, int n_in,
                              void* d_out, int out_size, void* d_ws, size_t ws_size,
                              hipStream_t stream) {
    const float* context  = (const float*)d_in[0];   // [N_NODES][VOCAB]
    const int*   adj_row  = (const int*)  d_in[1];   // [E]
    const int*   adj_col  = (const int*)  d_in[2];   // [E]
    const float* adj_val  = (const float*)d_in[3];   // [E]
    const float* ctx_w    = (const float*)d_in[4];   // [HID][VOCAB]
    const float* out_w    = (const float*)d_in[5];   // [VOCAB][HID]
    const float* out_b    = (const float*)d_in[6];   // [VOCAB]
    float*       out      = (float*)d_out;           // [N_NODES][VOCAB]

    // workspace layout (bytes, 16B-aligned blocks)
    char* ws = (char*)d_ws;
    float* support = (float*)ws;                              ws += (size_t)N_NODES * HID * 4;
    float* agg     = (float*)ws;                              ws += (size_t)N_NODES * HID * 4;
    int*   csr_ptr = (int*)ws;                                ws += ((size_t)N_NODES + 4) * 4;
    int*   cursor  = (int*)ws;                                ws += (size_t)N_NODES * 4;
    int*   ccol    = (int*)ws;                                ws += (size_t)N_EDGES * 4;
    float* cval    = (float*)ws;                              ws += (size_t)N_EDGES * 4;

    const dim3 blk(256);

    // GEMM1: support = context @ ctx_w^T   (M=50000, N=256, K=2048)
    dim3 g1((N_NODES + 127) / 128, HID / 128);
    gemm_bt<false, false><<<g1, blk, 0, stream>>>(
        context, ctx_w, nullptr, support, N_NODES, HID, VOCAB);

    // --- CSR build (overlaps GEMM1 only via stream order; all cheap) ---
    hipMemsetAsync(cursor, 0, (size_t)N_NODES * 4, stream);
    row_histogram<<<1024, blk, 0, stream>>>(adj_row, cursor, N_EDGES);
    exscan<<<1, 1024, 0, stream>>>(cursor, csr_ptr, N_NODES);
    hipMemsetAsync(cursor, 0, (size_t)N_NODES * 4, stream);
    csr_fill<<<1024, blk, 0, stream>>>(
        adj_row, adj_col, adj_val, csr_ptr, cursor, ccol, cval, N_EDGES);

    // SpMM gather: agg[r] = sum val * support[c]
    spmm_gather<<<(N_NODES + 3) / 4, blk, 0, stream>>>(
        csr_ptr, ccol, cval, support, agg, N_NODES);

    // GEMM2: out = relu(agg) @ out_w^T + out_b  (M=50000, N=2048, K=256)
    dim3 g2((N_NODES + 127) / 128, VOCAB / 128);
    gemm_bt<true, true><<<g2, blk, 0, stream>>>(
        agg, out_w, out_b, out, N_NODES, VOCAB, HID);
}

// Round 3
// 988.612 us; speedup vs baseline: 5.9734x; 1.1147x over previous
//
#include <hip/hip_runtime.h>
#include <hip/hip_bf16.h>

#define N_NODES 50000
#define VOCAB   2048
#define HID     256
#define N_EDGES 1600000

typedef __attribute__((ext_vector_type(8))) __bf16 bf16x8;
typedef __attribute__((ext_vector_type(4))) __bf16 bf16x4;
typedef __attribute__((ext_vector_type(4))) float  f32x4;

// ---------------------------------------------------------------------------
// GEMM with B^T input: C[M][N] = A[M][K] * B[N][K]^T (+ bias)
// bf16 MFMA 16x16x32, 128x256 tile, BK=64, 8 waves (2x4), fp32 in/out.
// LDS row stride 68 bf16 (136 B) -> bank = row*2 mod 32: 16-bank spread.
// ---------------------------------------------------------------------------
template<bool BIAS, bool SWZ>
__global__ __launch_bounds__(512, 4) void gemm_bt(
    const float* __restrict__ A,     // [M][K]
    const float* __restrict__ B,     // [N][K]
    const float* __restrict__ bias,  // [N] or nullptr
    float* __restrict__ C,           // [M][N]
    int M, int N, int K, int nby)
{
    constexpr int BM = 128, BN = 256, BK = 64, LDK = 68;
    __shared__ __bf16 sA[BM * LDK];   // 17408 B
    __shared__ __bf16 sB[BN * LDK];   // 34816 B  (total 52224 B -> 2 blocks/CU)

    const int tid  = threadIdx.x;
    const int lane = tid & 63;
    const int wid  = tid >> 6;        // 0..7
    const int wm   = wid >> 2;        // 0..1
    const int wn   = wid & 3;         // 0..3
    const int half = lane >> 4;       // 0..3
    const int r16  = lane & 15;

    // XCD-bijective block swizzle (m204): contiguous chunks per XCD
    int wg = blockIdx.x;
    if (SWZ) {
        const int nwg = gridDim.x;
        const int q = nwg >> 3, r = nwg & 7;
        const int x = wg & 7, o = wg >> 3;
        wg = (x < r ? x * (q + 1) : r * (q + 1) + (x - r) * q) + o;
    }
    const int m0 = (wg / nby) * BM;
    const int n0 = (wg % nby) * BN;

    f32x4 acc[4][4] = {};

    const int nkt = K / BK;
    for (int kt = 0; kt < nkt; ++kt) {
        const int k0 = kt * BK;
        // stage A(128x64) + B(256x64) fp32 -> bf16 LDS; 12 float4 per thread
        #pragma unroll
        for (int i = 0; i < 12; ++i) {
            const int s   = i * 512 + tid;   // 0..6143
            const int row = s >> 4;          // 16 float4 per row
            const int cg  = s & 15;
            float4 v;
            __bf16* dst;
            if (row < BM) {
                const int gr = m0 + row;
                v = (gr < M) ? *(const float4*)&A[(size_t)gr * K + k0 + cg * 4]
                             : make_float4(0.f, 0.f, 0.f, 0.f);
                dst = &sA[row * LDK + cg * 4];
            } else {
                const int br = n0 + row - BM;
                v = *(const float4*)&B[(size_t)br * K + k0 + cg * 4];
                dst = &sB[(row - BM) * LDK + cg * 4];
            }
            bf16x4 p = { (__bf16)v.x, (__bf16)v.y, (__bf16)v.z, (__bf16)v.w };
            *(bf16x4*)dst = p;
        }
        __syncthreads();

        #pragma unroll
        for (int kk = 0; kk < 2; ++kk) {
            bf16x8 af[4], bf[4];
            #pragma unroll
            for (int m = 0; m < 4; ++m)
                af[m] = *(const bf16x8*)&sA[(wm * 64 + m * 16 + r16) * LDK + kk * 32 + half * 8];
            #pragma unroll
            for (int n = 0; n < 4; ++n)
                bf[n] = *(const bf16x8*)&sB[(wn * 64 + n * 16 + r16) * LDK + kk * 32 + half * 8];
            #pragma unroll
            for (int m = 0; m < 4; ++m)
                #pragma unroll
                for (int n = 0; n < 4; ++n)
                    acc[m][n] = __builtin_amdgcn_mfma_f32_16x16x32_bf16(
                                    af[m], bf[n], acc[m][n], 0, 0, 0);
        }
        __syncthreads();
    }

    // epilogue: C/D layout col=lane&15, row=(lane>>4)*4+j (m89-verified)
    #pragma unroll
    for (int m = 0; m < 4; ++m) {
        const int rbase = m0 + wm * 64 + m * 16 + half * 4;
        #pragma unroll
        for (int j = 0; j < 4; ++j) {
            const int gr = rbase + j;
            if (gr >= M) continue;
            #pragma unroll
            for (int n = 0; n < 4; ++n) {
                const int gc = n0 + wn * 64 + n * 16 + r16;
                float o = acc[m][n][j];
                if (BIAS) o += bias[gc];
                C[(size_t)gr * N + gc] = o;
            }
        }
    }
}

// ---------------------------------------------------------------------------
// CSR build: histogram -> exclusive scan -> fill (col,val) packed as int2
// ---------------------------------------------------------------------------
__global__ __launch_bounds__(256) void row_histogram(
    const int* __restrict__ arow, int* __restrict__ cnt, int E)
{
    const int t = blockIdx.x * blockDim.x + threadIdx.x;
    const int n = gridDim.x * blockDim.x;
    for (int e = t; e < E; e += n)
        atomicAdd(&cnt[arow[e]], 1);
}

__global__ __launch_bounds__(1024) void exscan(
    const int* __restrict__ cnt, int* __restrict__ ptr, int n)
{
    __shared__ int s[1024];
    const int t = threadIdx.x;
    const int chunk = (n + 1023) / 1024;
    const int base  = t * chunk;
    int sum = 0;
    for (int i = 0; i < chunk; ++i) {
        const int idx = base + i;
        if (idx < n) sum += cnt[idx];
    }
    s[t] = sum;
    __syncthreads();
    for (int off = 1; off < 1024; off <<= 1) {
        int v = (t >= off) ? s[t - off] : 0;
        __syncthreads();
        s[t] += v;
        __syncthreads();
    }
    int run = (t == 0) ? 0 : s[t - 1];
    for (int i = 0; i < chunk; ++i) {
        const int idx = base + i;
        if (idx < n) { ptr[idx] = run; run += cnt[idx]; }
    }
    if (t == 1023) ptr[n] = run;
}

__global__ __launch_bounds__(256) void csr_fill(
    const int*   __restrict__ arow,
    const int*   __restrict__ acol,
    const float* __restrict__ aval,
    const int*   __restrict__ ptr,
    int*         __restrict__ cursor,   // zeroed
    int2*        __restrict__ cpair,    // {col, val-bits}
    int E)
{
    const int t = blockIdx.x * blockDim.x + threadIdx.x;
    const int n = gridDim.x * blockDim.x;
    for (int e = t; e < E; e += n) {
        const int r   = arow[e];
        const int pos = ptr[r] + atomicAdd(&cursor[r], 1);
        cpair[pos] = make_int2(acol[e], __float_as_int(aval[e]));
    }
}

// ---------------------------------------------------------------------------
// SpMM gather + relu: one wave per row; lane holds f32x4 of 256 hidden dims.
// ---------------------------------------------------------------------------
__global__ __launch_bounds__(256) void spmm_gather(
    const int*   __restrict__ ptr,
    const int2*  __restrict__ cpair,
    const float* __restrict__ support,
    float*       __restrict__ agg,     // relu'd
    int n)
{
    const int lane = threadIdx.x & 63;
    const int row  = blockIdx.x * 4 + (threadIdx.x >> 6);
    if (row >= n) return;
    const int beg = ptr[row];
    const int end = ptr[row + 1];

    f32x4 acc = {0.f, 0.f, 0.f, 0.f};
    int i = beg;
    for (; i + 8 <= end; i += 8) {
        #pragma unroll
        for (int u = 0; u < 8; ++u) {
            const int2  p = cpair[i + u];
            const float v = __int_as_float(p.y);
            const f32x4 s = *(const f32x4*)&support[(size_t)p.x * HID + lane * 4];
            acc += v * s;
        }
    }
    for (; i < end; ++i) {
        const int2  p = cpair[i];
        const float v = __int_as_float(p.y);
        const f32x4 s = *(const f32x4*)&support[(size_t)p.x * HID + lane * 4];
        acc += v * s;
    }
    f32x4 z = {0.f, 0.f, 0.f, 0.f};
    acc = __builtin_elementwise_max(acc, z);   // fused relu
    *(f32x4*)&agg[(size_t)row * HID + lane * 4] = acc;
}

extern "C" void kernel_launch(void* const* d_in, const int* in_sizes, int n_in,
                              void* d_out, int out_size, void* d_ws, size_t ws_size,
                              hipStream_t stream) {
    const float* context  = (const float*)d_in[0];
    const int*   adj_row  = (const int*)  d_in[1];
    const int*   adj_col  = (const int*)  d_in[2];
    const float* adj_val  = (const float*)d_in[3];
    const float* ctx_w    = (const float*)d_in[4];
    const float* out_w    = (const float*)d_in[5];
    const float* out_b    = (const float*)d_in[6];
    float*       out      = (float*)d_out;

    char* ws = (char*)d_ws;
    float* support = (float*)ws;   ws += (size_t)N_NODES * HID * 4;
    float* agg     = (float*)ws;   ws += (size_t)N_NODES * HID * 4;
    int*   csr_ptr = (int*)ws;     ws += ((size_t)N_NODES + 4) * 4;
    int*   cursor  = (int*)ws;     ws += (size_t)N_NODES * 4;
    int2*  cpair   = (int2*)ws;    ws += (size_t)N_EDGES * 8;

    const dim3 blk256(256), blk512(512);

    // GEMM1: support = context @ ctx_w^T  (M=50000, N=256, K=2048), 1 col-block
    gemm_bt<false, false><<<dim3((N_NODES + 127) / 128), blk512, 0, stream>>>(
        context, ctx_w, nullptr, support, N_NODES, HID, VOCAB, 1);

    // CSR build
    hipMemsetAsync(cursor, 0, (size_t)N_NODES * 4, stream);
    row_histogram<<<1024, blk256, 0, stream>>>(adj_row, cursor, N_EDGES);
    exscan<<<1, 1024, 0, stream>>>(cursor, csr_ptr, N_NODES);
    hipMemsetAsync(cursor, 0, (size_t)N_NODES * 4, stream);
    csr_fill<<<1024, blk256, 0, stream>>>(
        adj_row, adj_col, adj_val, csr_ptr, cursor, cpair, N_EDGES);

    // SpMM gather + relu
    spmm_gather<<<(N_NODES + 3) / 4, blk256, 0, stream>>>(
        csr_ptr, cpair, support, agg, N_NODES);

    // GEMM2: out = agg @ out_w^T + b  (M=50000, N=2048, K=256), 8 col-blocks
    gemm_bt<true, true><<<dim3(((N_NODES + 127) / 128) * 8), blk512, 0, stream>>>(
        agg, out_w, out_b, out, N_NODES, VOCAB, HID, 8);
}

// Round 4
// 871.762 us; speedup vs baseline: 6.7741x; 1.1340x over previous
//
#include <hip/hip_runtime.h>
#include <hip/hip_bf16.h>

#define N_NODES 50000
#define VOCAB   2048
#define HID     256
#define N_EDGES 1600000

typedef __attribute__((ext_vector_type(8))) __bf16 bf16x8;
typedef __attribute__((ext_vector_type(4))) __bf16 bf16x4;
typedef __attribute__((ext_vector_type(4))) float  f32x4;

__device__ __forceinline__ float bf2f(unsigned short u) {
    return __uint_as_float(((unsigned)u) << 16);
}

// ---------------------------------------------------------------------------
// one-time fp32 -> bf16 weight preconvert (2 MB total, ~5 us)
// ---------------------------------------------------------------------------
__global__ __launch_bounds__(256) void cvt_f32_bf16(
    const float* __restrict__ in, __bf16* __restrict__ out, int n4)
{
    const int t = blockIdx.x * 256 + threadIdx.x;
    if (t < n4) {
        const float4 v = ((const float4*)in)[t];
        bf16x4 p = { (__bf16)v.x, (__bf16)v.y, (__bf16)v.z, (__bf16)v.w };
        ((bf16x4*)out)[t] = p;
    }
}

// ---------------------------------------------------------------------------
// Pipelined GEMM, B^T input: C[M][N] = A[M][K] * B[N][K]^T (+bias)
// BM=64, BN=128, BK=64, 8 waves (2x4, 32x32 each), double-buffered LDS,
// per-tile: issue loads(t+1) -> MFMA(t) -> drain+ds_write -> 1 barrier.
// B always bf16 (preconverted). A fp32 (cvt in reg) or bf16 (direct copy).
// LDK=72: 144B row stride -> 16B-aligned ds ops, 2-way bank alias only.
// ---------------------------------------------------------------------------
template<bool A_F32, bool OUT_BF16, bool BIAS>
__global__ __launch_bounds__(512, 4) void gemm_p(
    const void*  __restrict__ Araw,   // [M][K] fp32 or bf16
    const __bf16* __restrict__ Bb,    // [N][K] bf16
    const float* __restrict__ bias,   // [N] or nullptr
    void*        __restrict__ Craw,   // [M][N] bf16 or fp32
    int M, int N, int K, int nby)
{
    constexpr int BM = 64, BN = 128, BK = 64, LDK = 72;
    __shared__ __bf16 sA[2][BM * LDK];   // 2 x  9216 B
    __shared__ __bf16 sB[2][BN * LDK];   // 2 x 18432 B  (total 55296 B)

    const int tid  = threadIdx.x;
    const int lane = tid & 63;
    const int wid  = tid >> 6;        // 0..7
    const int wm   = wid >> 2;        // 0..1
    const int wn   = wid & 3;         // 0..3
    const int half = lane >> 4;       // 0..3
    const int r16  = lane & 15;

    // XCD-bijective swizzle (m204): contiguous wg chunks per XCD
    int wg = blockIdx.x;
    {
        const int nwg = gridDim.x;
        const int q = nwg >> 3, r = nwg & 7;
        const int x = wg & 7, o = wg >> 3;
        wg = (x < r ? x * (q + 1) : r * (q + 1) + (x - r) * q) + o;
    }
    const int m0 = (wg / nby) * BM;
    const int n0 = (wg % nby) * BN;

    const float*  Af = (const float*)Araw;
    const __bf16* Ab = (const __bf16*)Araw;

    f32x4 acc[2][2] = {};
    float4 ra[2]; uint4 rab; uint4 rb[2];

    const int nkt = K / BK;

    auto LOAD = [&](int kt) {
        const int k0 = kt * BK;
        if constexpr (A_F32) {
            #pragma unroll
            for (int i = 0; i < 2; ++i) {
                const int s = i * 512 + tid;
                const int row = s >> 4, cg = s & 15;   // 64 rows x 16 float4
                const int gr = m0 + row;
                ra[i] = (gr < M) ? *(const float4*)&Af[(size_t)gr * K + k0 + cg * 4]
                                 : make_float4(0.f, 0.f, 0.f, 0.f);
            }
        } else {
            const int row = tid >> 3, cg = tid & 7;    // 64 rows x 8 bf16x8
            const int gr = m0 + row;
            rab = (gr < M) ? *(const uint4*)&Ab[(size_t)gr * K + k0 + cg * 8]
                           : make_uint4(0, 0, 0, 0);
        }
        #pragma unroll
        for (int i = 0; i < 2; ++i) {
            const int s = i * 512 + tid;
            const int row = s >> 3, cg = s & 7;        // 128 rows x 8 bf16x8
            rb[i] = *(const uint4*)&Bb[(size_t)(n0 + row) * K + k0 + cg * 8];
        }
    };

    auto WRITE = [&](int b) {
        if constexpr (A_F32) {
            #pragma unroll
            for (int i = 0; i < 2; ++i) {
                const int s = i * 512 + tid;
                const int row = s >> 4, cg = s & 15;
                bf16x4 p = { (__bf16)ra[i].x, (__bf16)ra[i].y,
                             (__bf16)ra[i].z, (__bf16)ra[i].w };
                *(bf16x4*)&sA[b][row * LDK + cg * 4] = p;
            }
        } else {
            *(uint4*)&sA[b][(tid >> 3) * LDK + (tid & 7) * 8] = rab;
        }
        #pragma unroll
        for (int i = 0; i < 2; ++i) {
            const int s = i * 512 + tid;
            const int row = s >> 3, cg = s & 7;
            *(uint4*)&sB[b][row * LDK + cg * 8] = rb[i];
        }
    };

    auto MFMA_STEP = [&](int b) {
        #pragma unroll
        for (int kk = 0; kk < 2; ++kk) {
            bf16x8 af[2], bf[2];
            #pragma unroll
            for (int m = 0; m < 2; ++m)
                af[m] = *(const bf16x8*)&sA[b][(wm * 32 + m * 16 + r16) * LDK + kk * 32 + half * 8];
            #pragma unroll
            for (int n = 0; n < 2; ++n)
                bf[n] = *(const bf16x8*)&sB[b][(wn * 32 + n * 16 + r16) * LDK + kk * 32 + half * 8];
            #pragma unroll
            for (int m = 0; m < 2; ++m)
                #pragma unroll
                for (int n = 0; n < 2; ++n)
                    acc[m][n] = __builtin_amdgcn_mfma_f32_16x16x32_bf16(
                                    af[m], bf[n], acc[m][n], 0, 0, 0);
        }
    };

    LOAD(0); WRITE(0); __syncthreads();
    int cur = 0;
    for (int kt = 1; kt < nkt; ++kt) {
        LOAD(kt);            // issue next tile's global loads (stay in flight)
        MFMA_STEP(cur);      // compute current tile (covers load latency)
        WRITE(cur ^ 1);      // vmcnt drain + cvt + ds_write into other buffer
        __syncthreads();
        cur ^= 1;
    }
    MFMA_STEP(cur);

    // epilogue: C/D layout col=lane&15, row=(lane>>4)*4+j (m89-verified)
    #pragma unroll
    for (int m = 0; m < 2; ++m) {
        #pragma unroll
        for (int j = 0; j < 4; ++j) {
            const int gr = m0 + wm * 32 + m * 16 + half * 4 + j;
            if (gr >= M) continue;
            #pragma unroll
            for (int n = 0; n < 2; ++n) {
                const int gc = n0 + wn * 32 + n * 16 + r16;
                float o = acc[m][n][j];
                if constexpr (BIAS) o += bias[gc];
                if constexpr (OUT_BF16)
                    ((__bf16*)Craw)[(size_t)gr * N + gc] = (__bf16)o;
                else
                    ((float*)Craw)[(size_t)gr * N + gc] = o;
            }
        }
    }
}

// ---------------------------------------------------------------------------
// CSR build: histogram -> exclusive scan (also seeds cursor) -> fill
// ---------------------------------------------------------------------------
__global__ __launch_bounds__(256) void row_histogram(
    const int* __restrict__ arow, int* __restrict__ cnt, int E)
{
    const int t = blockIdx.x * blockDim.x + threadIdx.x;
    const int n = gridDim.x * blockDim.x;
    for (int e = t; e < E; e += n)
        atomicAdd(&cnt[arow[e]], 1);
}

// cnt_cur: in = counts, out = start offsets (cursor); ptr: row pointers
__global__ __launch_bounds__(1024) void exscan(
    int* __restrict__ cnt_cur, int* __restrict__ ptr, int n)
{
    __shared__ int s[1024];
    const int t = threadIdx.x;
    const int chunk = (n + 1023) / 1024;
    const int base  = t * chunk;
    int sum = 0;
    for (int i = 0; i < chunk; ++i) {
        const int idx = base + i;
        if (idx < n) sum += cnt_cur[idx];
    }
    s[t] = sum;
    __syncthreads();
    for (int off = 1; off < 1024; off <<= 1) {
        int v = (t >= off) ? s[t - off] : 0;
        __syncthreads();
        s[t] += v;
        __syncthreads();
    }
    int run = (t == 0) ? 0 : s[t - 1];
    for (int i = 0; i < chunk; ++i) {
        const int idx = base + i;
        if (idx < n) {
            const int c = cnt_cur[idx];
            ptr[idx] = run;
            cnt_cur[idx] = run;   // cursor seed
            run += c;
        }
    }
    if (t == 1023) ptr[n] = run;
}

__global__ __launch_bounds__(256) void csr_fill(
    const int*   __restrict__ arow,
    const int*   __restrict__ acol,
    const float* __restrict__ aval,
    int*         __restrict__ cursor,   // seeded with start offsets
    int2*        __restrict__ cpair,    // {col, val-bits}
    int E)
{
    const int t = blockIdx.x * blockDim.x + threadIdx.x;
    const int n = gridDim.x * blockDim.x;
    for (int e = t; e < E; e += n) {
        const int pos = atomicAdd(&cursor[arow[e]], 1);
        cpair[pos] = make_int2(acol[e], __float_as_int(aval[e]));
    }
}

// ---------------------------------------------------------------------------
// SpMM gather + relu, bf16 support -> bf16 agg. One wave per row; lane owns
// 4 hidden dims (8B loads; wave reads 512B contiguous per edge).
// ---------------------------------------------------------------------------
__global__ __launch_bounds__(256) void spmm_gather(
    const int*    __restrict__ ptr,
    const int2*   __restrict__ cpair,
    const __bf16* __restrict__ support,
    __bf16*       __restrict__ agg,
    int n)
{
    const int lane = threadIdx.x & 63;
    const int row  = blockIdx.x * 4 + (threadIdx.x >> 6);
    if (row >= n) return;
    const int beg = ptr[row], end = ptr[row + 1];

    f32x4 acc = {0.f, 0.f, 0.f, 0.f};
    int i = beg;
    for (; i + 8 <= end; i += 8) {
        #pragma unroll
        for (int u = 0; u < 8; ++u) {
            const int2  p = cpair[i + u];
            const float v = __int_as_float(p.y);
            const ushort4 s = *(const ushort4*)&support[(size_t)p.x * HID + lane * 4];
            acc.x += v * bf2f(s.x);
            acc.y += v * bf2f(s.y);
            acc.z += v * bf2f(s.z);
            acc.w += v * bf2f(s.w);
        }
    }
    for (; i < end; ++i) {
        const int2  p = cpair[i];
        const float v = __int_as_float(p.y);
        const ushort4 s = *(const ushort4*)&support[(size_t)p.x * HID + lane * 4];
        acc.x += v * bf2f(s.x);
        acc.y += v * bf2f(s.y);
        acc.z += v * bf2f(s.z);
        acc.w += v * bf2f(s.w);
    }
    bf16x4 o = { (__bf16)fmaxf(acc.x, 0.f), (__bf16)fmaxf(acc.y, 0.f),
                 (__bf16)fmaxf(acc.z, 0.f), (__bf16)fmaxf(acc.w, 0.f) };
    *(bf16x4*)&agg[(size_t)row * HID + lane * 4] = o;
}

extern "C" void kernel_launch(void* const* d_in, const int* in_sizes, int n_in,
                              void* d_out, int out_size, void* d_ws, size_t ws_size,
                              hipStream_t stream) {
    const float* context  = (const float*)d_in[0];
    const int*   adj_row  = (const int*)  d_in[1];
    const int*   adj_col  = (const int*)  d_in[2];
    const float* adj_val  = (const float*)d_in[3];
    const float* ctx_w    = (const float*)d_in[4];
    const float* out_w    = (const float*)d_in[5];
    const float* out_b    = (const float*)d_in[6];
    float*       out      = (float*)d_out;

    char* ws = (char*)d_ws;
    __bf16* support_b = (__bf16*)ws;  ws += (size_t)N_NODES * HID * 2;
    __bf16* agg_b     = (__bf16*)ws;  ws += (size_t)N_NODES * HID * 2;
    __bf16* ctxw_b    = (__bf16*)ws;  ws += (size_t)HID * VOCAB * 2;
    __bf16* outw_b    = (__bf16*)ws;  ws += (size_t)VOCAB * HID * 2;
    int*    csr_ptr   = (int*)ws;     ws += ((size_t)N_NODES + 16) * 4;
    int*    cursor    = (int*)ws;     ws += (size_t)N_NODES * 4;
    int2*   cpair     = (int2*)ws;    ws += (size_t)N_EDGES * 8;

    constexpr int MT = (N_NODES + 63) / 64;   // 782 m-tiles

    // weight preconverts
    cvt_f32_bf16<<<(HID * VOCAB / 4 + 255) / 256, 256, 0, stream>>>(
        ctx_w, ctxw_b, HID * VOCAB / 4);
    cvt_f32_bf16<<<(VOCAB * HID / 4 + 255) / 256, 256, 0, stream>>>(
        out_w, outw_b, VOCAB * HID / 4);

    // GEMM1: support_b = bf16( context @ ctx_w^T )  (M=50000, N=256, K=2048)
    gemm_p<true, true, false><<<dim3(MT * 2), dim3(512), 0, stream>>>(
        context, ctxw_b, nullptr, support_b, N_NODES, HID, VOCAB, 2);

    // CSR build
    hipMemsetAsync(cursor, 0, (size_t)N_NODES * 4, stream);
    row_histogram<<<1024, 256, 0, stream>>>(adj_row, cursor, N_EDGES);
    exscan<<<1, 1024, 0, stream>>>(cursor, csr_ptr, N_NODES);
    csr_fill<<<1024, 256, 0, stream>>>(
        adj_row, adj_col, adj_val, cursor, cpair, N_EDGES);

    // SpMM gather + relu -> agg_b
    spmm_gather<<<(N_NODES + 3) / 4, 256, 0, stream>>>(
        csr_ptr, cpair, support_b, agg_b, N_NODES);

    // GEMM2: out = agg_b @ out_w^T + b  (M=50000, N=2048, K=256)
    gemm_p<false, false, true><<<dim3(MT * 16), dim3(512), 0, stream>>>(
        agg_b, outw_b, out_b, out, N_NODES, VOCAB, HID, 16);
}